// Round 5
// baseline (506.656 us; speedup 1.0000x reference)
//
#include <hip/hip_runtime.h>
#include <hip/hip_bf16.h>

#define NN 50000
#define EE 800000
#define ETOT 850000
#define BB 512
#define CAP 64     // bucket capacity per node; Poisson(17) => P(deg>63) ~ 1e-18
#define NPART 8    // dst-range partitions (one per XCD under round-robin dispatch)
#define DPP 6250   // nodes per partition = NN/NPART
#define NC ((size_t)NN * CAP)

typedef __hip_bfloat16 bf16;
typedef __attribute__((ext_vector_type(8))) __bf16 v8bf;
typedef __attribute__((ext_vector_type(4))) float f32x4;

__device__ __forceinline__ float lo2f(unsigned int u) {
    return __uint_as_float(u << 16);
}
__device__ __forceinline__ float hi2f(unsigned int u) {
    return __uint_as_float(u & 0xffff0000u);
}
__device__ __forceinline__ float us2f(unsigned short u) {
    return __uint_as_float(((unsigned int)u) << 16);
}
__device__ __forceinline__ unsigned short f2bfbits(float f) {
    bf16 h = __float2bfloat16(f);
    return *reinterpret_cast<unsigned short*>(&h);
}
__device__ __forceinline__ float lrelu_exp(float ev) {
    ev = ev > 0.f ? ev : 0.2f * ev;
    return __expf(fminf(ev, 80.f));
}

// ---------------- prep: weight transpose+cvt AND zero deg ----------------
__global__ void k_prep(const float* __restrict__ W1, const float* __restrict__ W2,
                       bf16* __restrict__ wt1, bf16* __restrict__ wt2,
                       int* __restrict__ deg) {
    int idx = blockIdx.x * blockDim.x + threadIdx.x;  // 65536 threads
    if (idx < 256 * 128) {
        int c = idx >> 7, k = idx & 127;
        wt1[idx] = __float2bfloat16(W1[k * 256 + c]);
    } else {
        int j = idx - 256 * 128;
        int c = j >> 8, k = j & 255;
        wt2[j] = __float2bfloat16(W2[k * 128 + c]);
    }
    if (idx < NN) deg[idx] = 0;
}

// ---------------- XCD-partitioned bucket scatter (csrc ushort: NN<65536) --------
__global__ void k_scatter(const int* __restrict__ srcArr, const int* __restrict__ dstArr,
                          int* __restrict__ deg, unsigned short* __restrict__ csrc) {
    int part = blockIdx.x & (NPART - 1);
    int e = (blockIdx.x >> 3) * 256 + threadIdx.x;
    if (e >= ETOT) return;
    int d, s;
    if (e < EE) { d = dstArr[e]; s = srcArr[e]; }
    else        { d = e - EE;    s = d; }
    d = min(max(d, 0), NN - 1);
    s = min(max(s, 0), NN - 1);
    int lo = part * DPP;
    if (d >= lo && d < lo + DPP) {
        int p = atomicAdd(&deg[d], 1);
        if (p < CAP) csrc[d * CAP + p] = (unsigned short)s;
    }
}

// ---------------- Layer 1 GEMM via MFMA: 32 nodes/block; h1 now SLICE-MAJOR ----------
// h1s[slice][node][32 cols] bf16, slice = col>>5: a gather slice is a compact 3.2MB
// region (fits one XCD's 4MB L2), no 128B-line straddle into other slices.
__global__ __launch_bounds__(256, 2)
void k_gemm1(const float* __restrict__ x, const bf16* __restrict__ wt1,
             const float* __restrict__ aw_s, const float* __restrict__ aw_d,
             bf16* __restrict__ h1s, float* __restrict__ as1,
             float* __restrict__ ad1) {
    int n0 = blockIdx.x * 32;
    int t = threadIdx.x;
    __shared__ bf16 xs[32 * 136];
    for (int i = 0; i < 4; i++) {
        int idx = t + 256 * i;
        int r = idx >> 5, c4 = idx & 31;
        float4 v = make_float4(0.f, 0.f, 0.f, 0.f);
        if (n0 + r < NN) v = *(const float4*)(x + (size_t)(n0 + r) * 128 + c4 * 4);
        ushort4 o;
        o.x = f2bfbits(v.x); o.y = f2bfbits(v.y);
        o.z = f2bfbits(v.z); o.w = f2bfbits(v.w);
        *(ushort4*)(&xs[r * 136 + c4 * 4]) = o;
    }
    __syncthreads();

    int wv = t >> 6, lane = t & 63;
    int q = lane >> 4, r16 = lane & 15;
    int rowBase = (wv & 1) * 16;
    int colBase = (wv >> 1) * 128;

    f32x4 acc[8];
#pragma unroll
    for (int ct = 0; ct < 8; ct++) acc[ct] = (f32x4){0.f, 0.f, 0.f, 0.f};

#pragma unroll
    for (int kt = 0; kt < 4; kt++) {
        v8bf va = *(const v8bf*)(&xs[(rowBase + r16) * 136 + kt * 32 + q * 8]);
#pragma unroll
        for (int ct = 0; ct < 8; ct++) {
            v8bf vb = *(const v8bf*)(wt1 + (size_t)(colBase + ct * 16 + r16) * 128 + kt * 32 + q * 8);
            acc[ct] = __builtin_amdgcn_mfma_f32_16x16x32_bf16(va, vb, acc[ct], 0, 0, 0);
        }
    }

    float wsv[8], wdv[8];
#pragma unroll
    for (int ct = 0; ct < 8; ct++) {
        int col = colBase + ct * 16 + r16;
        wsv[ct] = aw_s[col];
        wdv[ct] = aw_d[col];
    }

    float ps[4][2], pd[4][2];
#pragma unroll
    for (int reg = 0; reg < 4; reg++) {
        ps[reg][0] = 0.f; ps[reg][1] = 0.f;
        pd[reg][0] = 0.f; pd[reg][1] = 0.f;
    }

#pragma unroll
    for (int reg = 0; reg < 4; reg++) {
        int node = n0 + rowBase + q * 4 + reg;
        bool ok = node < NN;
#pragma unroll
        for (int ct = 0; ct < 8; ct++) {
            float v = acc[ct][reg];
            int col = colBase + ct * 16 + r16;
            if (ok) h1s[((size_t)(col >> 5) * NN + node) * 32 + (col & 31)] = __float2bfloat16(v);
            ps[reg][ct >> 2] += v * wsv[ct];
            pd[reg][ct >> 2] += v * wdv[ct];
        }
    }

#pragma unroll
    for (int reg = 0; reg < 4; reg++) {
        int node = n0 + rowBase + q * 4 + reg;
        bool ok = node < NN;
#pragma unroll
        for (int lh = 0; lh < 2; lh++) {
            float a = ps[reg][lh], b = pd[reg][lh];
            for (int mask = 1; mask <= 8; mask <<= 1) {
                a += __shfl_xor(a, mask);
                b += __shfl_xor(b, mask);
            }
            if (r16 == 0 && ok) {
                int head = (wv >> 1) * 2 + lh;
                as1[node * 4 + head] = a;
                ad1[node * 4 + head] = b;
            }
        }
    }
}

// ---------------- edge-weight precompute L1: pw1[head][n][j] = (src<<16)|bf16(w) ----
// Removes csrc/as1/ad1/exp from the gather's per-slice loop (round-4 failure modes
// 2+3). Non-temporal stores keep the 51MB stream out of L2.
__global__ __launch_bounds__(256, 8)
void k_edgew1(const unsigned short* __restrict__ csrc, const int* __restrict__ deg,
              const float* __restrict__ as1, const float* __restrict__ ad1,
              unsigned int* __restrict__ pw1) {
    int wv = threadIdx.x >> 6;
    int n = blockIdx.x * 4 + wv;        // NN % 4 == 0
    int l = threadIdx.x & 63;
    int cnt = min(deg[n], CAP);
    if (l >= cnt) return;
    int s = (int)csrc[(size_t)n * CAP + l];
    float4 as = *(const float4*)&as1[s * 4];
    float4 ad = *(const float4*)&ad1[n * 4];
    unsigned int sb = (unsigned int)s << 16;
    size_t o = (size_t)n * CAP + l;
    __builtin_nontemporal_store(sb | f2bfbits(lrelu_exp(as.x + ad.x)), pw1 + 0 * NC + o);
    __builtin_nontemporal_store(sb | f2bfbits(lrelu_exp(as.y + ad.y)), pw1 + 1 * NC + o);
    __builtin_nontemporal_store(sb | f2bfbits(lrelu_exp(as.z + ad.z)), pw1 + 2 * NC + o);
    __builtin_nontemporal_store(sb | f2bfbits(lrelu_exp(as.w + ad.w)), pw1 + 3 * NC + o);
}

// ---------------- Layer 1 gather: slice-per-XCD, subgroup-serial, NO LDS.
// slice = blockIdx&7 -> one XCD. 16 lanes = one node's 32-col slice (lane=2 cols);
// 16 subgroups/block = 16 nodes. Weights broadcast within subgroup -> ssum needs no
// reduction. Inner loop touches ONLY resident h1s slice + sequential pw1 stream.
__global__ __launch_bounds__(256, 8)
void k_gather1(const unsigned int* __restrict__ pw1, const int* __restrict__ deg,
               const bf16* __restrict__ h1s, const float* __restrict__ b1,
               bf16* __restrict__ x2) {
    int slice = blockIdx.x & 7;
    int ng = blockIdx.x >> 3;            // 0..3124
    int t = threadIdx.x;
    int sub = t >> 4;                    // node subgroup 0..15
    int c = t & 15;                      // column-pair within slice
    int n = ng * 16 + sub;               // NN % 16 == 0
    int head = slice >> 1;
    int cnt = min(deg[n], CAP);
    const unsigned int* base = pw1 + (size_t)head * NC + (size_t)n * CAP;
    const char* hsc = (const char*)h1s;
    unsigned int tconst = (unsigned int)slice * (NN * 64) + (unsigned int)c * 4;
    float a0 = 0.f, a1 = 0.f, ssum = 0.f;
    int j = 0;
    for (; j + 1 < cnt; j += 2) {
        unsigned long long pv = __builtin_nontemporal_load((const unsigned long long*)(base + j));
        unsigned int p0 = (unsigned int)pv, p1 = (unsigned int)(pv >> 32);
        unsigned int o0 = ((p0 & 0xffff0000u) >> 10) + tconst;   // (src<<6) + tconst
        unsigned int o1 = ((p1 & 0xffff0000u) >> 10) + tconst;
        float w0 = us2f((unsigned short)(p0 & 0xffffu));
        float w1 = us2f((unsigned short)(p1 & 0xffffu));
        unsigned int u0 = *(const unsigned int*)(hsc + o0);
        unsigned int u1 = *(const unsigned int*)(hsc + o1);
        ssum += w0 + w1;
        a0 = fmaf(w0, lo2f(u0), a0); a1 = fmaf(w0, hi2f(u0), a1);
        a0 = fmaf(w1, lo2f(u1), a0); a1 = fmaf(w1, hi2f(u1), a1);
    }
    if (j < cnt) {
        unsigned int p0 = __builtin_nontemporal_load(base + j);
        unsigned int o0 = ((p0 & 0xffff0000u) >> 10) + tconst;
        float w0 = us2f((unsigned short)(p0 & 0xffffu));
        unsigned int u0 = *(const unsigned int*)(hsc + o0);
        ssum += w0;
        a0 = fmaf(w0, lo2f(u0), a0); a1 = fmaf(w0, hi2f(u0), a1);
    }
    float inv = 1.f / fmaxf(ssum, 1e-35f);
    int col = slice * 32 + c * 2;
    float2 bv = *(const float2*)&b1[col];
    float r0 = a0 * inv + bv.x;
    float r1 = a1 * inv + bv.y;
    r0 = r0 > 0.f ? r0 : (__expf(r0) - 1.f);
    r1 = r1 > 0.f ? r1 : (__expf(r1) - 1.f);
    unsigned int packed = (unsigned int)f2bfbits(r0) | ((unsigned int)f2bfbits(r1) << 16);
    __builtin_nontemporal_store(packed,
        (unsigned int*)((unsigned short*)x2 + (size_t)n * 256 + col));
}

// ---------------- Layer 2 GEMM via MFMA: 32 nodes/block; h2 SLICE-MAJOR [4][N][32] ----
__global__ __launch_bounds__(256, 2)
void k_gemm2(const bf16* __restrict__ x2, const bf16* __restrict__ wt2,
             const float* __restrict__ aw_s, const float* __restrict__ aw_d,
             bf16* __restrict__ h2s, float* __restrict__ as2,
             float* __restrict__ ad2) {
    int n0 = blockIdx.x * 32;
    int t = threadIdx.x;
    __shared__ bf16 xs[32 * 264];
    __shared__ float psPart[32][2];
    __shared__ float pdPart[32][2];
    for (int i = 0; i < 4; i++) {
        int idx = t + 256 * i;
        int r = idx >> 5, c8 = idx & 31;
        uint4 v;
        if (n0 + r < NN) v = *(const uint4*)(x2 + (size_t)(n0 + r) * 256 + c8 * 8);
        else             v = make_uint4(0, 0, 0, 0);
        *(uint4*)(&xs[r * 264 + c8 * 8]) = v;
    }
    __syncthreads();

    int wv = t >> 6, lane = t & 63;
    int q = lane >> 4, r16 = lane & 15;
    int rowBase = (wv & 1) * 16;
    int colBase = (wv >> 1) * 64;

    f32x4 acc[4];
#pragma unroll
    for (int ct = 0; ct < 4; ct++) acc[ct] = (f32x4){0.f, 0.f, 0.f, 0.f};

#pragma unroll
    for (int kt = 0; kt < 8; kt++) {
        v8bf va = *(const v8bf*)(&xs[(rowBase + r16) * 264 + kt * 32 + q * 8]);
#pragma unroll
        for (int ct = 0; ct < 4; ct++) {
            v8bf vb = *(const v8bf*)(wt2 + (size_t)(colBase + ct * 16 + r16) * 256 + kt * 32 + q * 8);
            acc[ct] = __builtin_amdgcn_mfma_f32_16x16x32_bf16(va, vb, acc[ct], 0, 0, 0);
        }
    }

    float wsv[4], wdv[4];
#pragma unroll
    for (int ct = 0; ct < 4; ct++) {
        int col = colBase + ct * 16 + r16;
        wsv[ct] = aw_s[col];
        wdv[ct] = aw_d[col];
    }

#pragma unroll
    for (int reg = 0; reg < 4; reg++) {
        int node = n0 + rowBase + q * 4 + reg;
        bool ok = node < NN;
        float ps = 0.f, pd = 0.f;
#pragma unroll
        for (int ct = 0; ct < 4; ct++) {
            float v = acc[ct][reg];
            int col = colBase + ct * 16 + r16;
            if (ok) h2s[((size_t)(col >> 5) * NN + node) * 32 + (col & 31)] = __float2bfloat16(v);
            ps += v * wsv[ct];
            pd += v * wdv[ct];
        }
        for (int mask = 1; mask <= 8; mask <<= 1) {
            ps += __shfl_xor(ps, mask);
            pd += __shfl_xor(pd, mask);
        }
        if (r16 == 0) {
            int li = rowBase + q * 4 + reg;
            psPart[li][wv >> 1] = ps;
            pdPart[li][wv >> 1] = pd;
        }
    }
    __syncthreads();
    if (t < 32) {
        int node = n0 + t;
        if (node < NN) {
            as2[node] = psPart[t][0] + psPart[t][1];
            ad2[node] = pdPart[t][0] + pdPart[t][1];
        }
    }
}

// ---------------- edge-weight precompute L2 (single head) ----------------
__global__ __launch_bounds__(256, 8)
void k_edgew2(const unsigned short* __restrict__ csrc, const int* __restrict__ deg,
              const float* __restrict__ as2, const float* __restrict__ ad2,
              unsigned int* __restrict__ pw2) {
    int wv = threadIdx.x >> 6;
    int n = blockIdx.x * 4 + wv;
    int l = threadIdx.x & 63;
    int cnt = min(deg[n], CAP);
    if (l >= cnt) return;
    int s = (int)csrc[(size_t)n * CAP + l];
    float w = lrelu_exp(as2[s] + ad2[n]);
    __builtin_nontemporal_store(((unsigned int)s << 16) | f2bfbits(w),
                                pw2 + (size_t)n * CAP + l);
}

// ---------------- Layer 2 gather: 4 slices of h2s, same structure ----------------
__global__ __launch_bounds__(256, 8)
void k_gather2(const unsigned int* __restrict__ pw2, const int* __restrict__ deg,
               const bf16* __restrict__ h2s, const float* __restrict__ b2,
               bf16* __restrict__ hf) {
    int slice = blockIdx.x & 3;
    int ng = blockIdx.x >> 2;            // 0..3124
    int t = threadIdx.x;
    int sub = t >> 4;
    int c = t & 15;
    int n = ng * 16 + sub;
    int cnt = min(deg[n], CAP);
    const unsigned int* base = pw2 + (size_t)n * CAP;
    const char* hsc = (const char*)h2s;
    unsigned int tconst = (unsigned int)slice * (NN * 64) + (unsigned int)c * 4;
    float a0 = 0.f, a1 = 0.f, ssum = 0.f;
    int j = 0;
    for (; j + 1 < cnt; j += 2) {
        unsigned long long pv = __builtin_nontemporal_load((const unsigned long long*)(base + j));
        unsigned int p0 = (unsigned int)pv, p1 = (unsigned int)(pv >> 32);
        unsigned int o0 = ((p0 & 0xffff0000u) >> 10) + tconst;
        unsigned int o1 = ((p1 & 0xffff0000u) >> 10) + tconst;
        float w0 = us2f((unsigned short)(p0 & 0xffffu));
        float w1 = us2f((unsigned short)(p1 & 0xffffu));
        unsigned int u0 = *(const unsigned int*)(hsc + o0);
        unsigned int u1 = *(const unsigned int*)(hsc + o1);
        ssum += w0 + w1;
        a0 = fmaf(w0, lo2f(u0), a0); a1 = fmaf(w0, hi2f(u0), a1);
        a0 = fmaf(w1, lo2f(u1), a0); a1 = fmaf(w1, hi2f(u1), a1);
    }
    if (j < cnt) {
        unsigned int p0 = __builtin_nontemporal_load(base + j);
        unsigned int o0 = ((p0 & 0xffff0000u) >> 10) + tconst;
        float w0 = us2f((unsigned short)(p0 & 0xffffu));
        unsigned int u0 = *(const unsigned int*)(hsc + o0);
        ssum += w0;
        a0 = fmaf(w0, lo2f(u0), a0); a1 = fmaf(w0, hi2f(u0), a1);
    }
    float inv = 1.f / fmaxf(ssum, 1e-35f);
    int col = slice * 32 + c * 2;
    float2 bv = *(const float2*)&b2[col];
    float r0 = a0 * inv + bv.x;
    float r1 = a1 * inv + bv.y;
    r0 = r0 > 0.f ? r0 : (__expf(r0) - 1.f);
    r1 = r1 > 0.f ? r1 : (__expf(r1) - 1.f);
    unsigned int packed = (unsigned int)f2bfbits(r0) | ((unsigned int)f2bfbits(r1) << 16);
    __builtin_nontemporal_store(packed,
        (unsigned int*)((unsigned short*)hf + (size_t)n * 128 + col));
}

// ---------------- fused mean-pool + linear + sigmoid (batch SORTED; bf16 input) ----------------
__global__ void k_pool(const bf16* __restrict__ hf, const int* __restrict__ batch,
                       const float* __restrict__ Wl, const float* __restrict__ bl,
                       float* __restrict__ out) {
    int b = blockIdx.x;   // 0..511
    int t = threadIdx.x;  // 0..127
    int lo = 0, hi = NN;
    while (lo < hi) { int m = (lo + hi) >> 1; if (batch[m] < b) lo = m + 1; else hi = m; }
    int start = lo;
    int lo2 = start, hi2 = NN;
    while (lo2 < hi2) { int m = (lo2 + hi2) >> 1; if (batch[m] < b + 1) lo2 = m + 1; else hi2 = m; }
    int end = lo2;
    const unsigned short* hu = (const unsigned short*)hf;
    float sum = 0.f;
    for (int n = start; n < end; n++) sum += us2f(hu[(size_t)n * 128 + t]);
    int c = end - start;
    float g = sum / (float)(c > 0 ? c : 1);
    float p = g * Wl[t];
    for (int o = 32; o > 0; o >>= 1) p += __shfl_down(p, o);
    __shared__ float red[2];
    if ((t & 63) == 0) red[t >> 6] = p;
    __syncthreads();
    if (t == 0) {
        float acc = red[0] + red[1] + bl[0];
        out[b] = 1.f / (1.f + __expf(-acc));
    }
}

extern "C" void kernel_launch(void* const* d_in, const int* in_sizes, int n_in,
                              void* d_out, int out_size, void* d_ws, size_t ws_size,
                              hipStream_t stream) {
    const float* x = (const float*)d_in[0];
    const int* ei = (const int*)d_in[1];
    const int* batch = (const int*)d_in[2];
    const float* W1 = (const float*)d_in[3];
    const float* aw_s1 = (const float*)d_in[4];
    const float* aw_d1 = (const float*)d_in[5];
    const float* b1 = (const float*)d_in[6];
    const float* W2 = (const float*)d_in[7];
    const float* aw_s2 = (const float*)d_in[8];
    const float* aw_d2 = (const float*)d_in[9];
    const float* b2 = (const float*)d_in[10];
    const float* Wl = (const float*)d_in[11];
    const float* bl = (const float*)d_in[12];
    const int* srcArr = ei;
    const int* dstArr = ei + EE;

    char* w = (char*)d_ws;
    size_t off = 0;
    auto alloc = [&](size_t bytes) -> void* {
        void* p = (void*)(w + off);
        off = (off + bytes + 255) & ~(size_t)255;
        return p;
    };
    bf16* bufA = (bf16*)alloc((size_t)NN * 256 * 2);   // h1s [8][N][32]; later h2s [4][N][32]
    bf16* bufB = (bf16*)alloc((size_t)NN * 256 * 2);   // x2 [N][256]; later hf [N][128]
    unsigned short* csrc = (unsigned short*)alloc(NC * 2);       // 6.4 MB
    unsigned int* pw1 = (unsigned int*)alloc(4 * NC * 4);        // 51.2 MB
    unsigned int* pw2 = (unsigned int*)alloc(NC * 4);            // 12.8 MB
    float* as1 = (float*)alloc((size_t)NN * 4 * 4);
    float* ad1 = (float*)alloc((size_t)NN * 4 * 4);
    float* as2 = (float*)alloc((size_t)NN * 4);
    float* ad2 = (float*)alloc((size_t)NN * 4);
    int* deg = (int*)alloc((size_t)NN * 4);
    bf16* wt1 = (bf16*)alloc((size_t)256 * 128 * 2);
    bf16* wt2 = (bf16*)alloc((size_t)128 * 256 * 2);
    (void)ws_size;

    k_prep<<<256, 256, 0, stream>>>(W1, W2, wt1, wt2, deg);
    int chunks = (ETOT + 255) / 256;
    k_scatter<<<chunks * NPART, 256, 0, stream>>>(srcArr, dstArr, deg, csrc);

    bf16* h1s = bufA;
    bf16* x2 = bufB;
    k_gemm1<<<(NN + 31) / 32, 256, 0, stream>>>(x, wt1, aw_s1, aw_d1, h1s, as1, ad1);
    k_edgew1<<<NN / 4, 256, 0, stream>>>(csrc, deg, as1, ad1, pw1);
    k_gather1<<<(NN / 16) * 8, 256, 0, stream>>>(pw1, deg, h1s, b1, x2);

    bf16* h2s = bufA;  // h1s dead after gather1
    k_gemm2<<<(NN + 31) / 32, 256, 0, stream>>>(x2, wt2, aw_s2, aw_d2, h2s, as2, ad2);
    k_edgew2<<<NN / 4, 256, 0, stream>>>(csrc, deg, as2, ad2, pw2);

    bf16* hf = bufB;   // x2 dead after gemm2
    k_gather2<<<(NN / 16) * 4, 256, 0, stream>>>(pw2, deg, h2s, b2, hf);

    k_pool<<<BB, 128, 0, stream>>>(hf, batch, Wl, bl, (float*)d_out);
}

// Round 6
// 365.264 us; speedup vs baseline: 1.3871x; 1.3871x over previous
//
#include <hip/hip_runtime.h>
#include <hip/hip_bf16.h>

#define NN 50000
#define EE 800000
#define ETOT 850000
#define BB 512
#define CAP 64     // bucket capacity per node; Poisson(17) => P(deg>63) ~ 1e-18
#define NPART 8    // dst-range partitions (one per XCD under round-robin dispatch)
#define DPP 6250   // nodes per partition = NN/NPART
#define NC ((size_t)NN * CAP)

typedef __hip_bfloat16 bf16;
typedef __attribute__((ext_vector_type(8))) __bf16 v8bf;
typedef __attribute__((ext_vector_type(4))) float f32x4;

__device__ __forceinline__ float lo2f(unsigned int u) {
    return __uint_as_float(u << 16);
}
__device__ __forceinline__ float hi2f(unsigned int u) {
    return __uint_as_float(u & 0xffff0000u);
}
__device__ __forceinline__ float us2f(unsigned short u) {
    return __uint_as_float(((unsigned int)u) << 16);
}
__device__ __forceinline__ unsigned short f2bfbits(float f) {
    bf16 h = __float2bfloat16(f);
    return *reinterpret_cast<unsigned short*>(&h);
}
__device__ __forceinline__ float lrelu_exp(float ev) {
    ev = ev > 0.f ? ev : 0.2f * ev;
    return __expf(fminf(ev, 80.f));
}

// ---------------- prep: weight transpose+cvt AND zero deg ----------------
__global__ void k_prep(const float* __restrict__ W1, const float* __restrict__ W2,
                       bf16* __restrict__ wt1, bf16* __restrict__ wt2,
                       int* __restrict__ deg) {
    int idx = blockIdx.x * blockDim.x + threadIdx.x;  // 65536 threads
    if (idx < 256 * 128) {
        int c = idx >> 7, k = idx & 127;
        wt1[idx] = __float2bfloat16(W1[k * 256 + c]);
    } else {
        int j = idx - 256 * 128;
        int c = j >> 8, k = j & 255;
        wt2[j] = __float2bfloat16(W2[k * 128 + c]);
    }
    if (idx < NN) deg[idx] = 0;
}

// ---------------- XCD-partitioned bucket scatter (csrc ushort: NN<65536) --------
__global__ void k_scatter(const int* __restrict__ srcArr, const int* __restrict__ dstArr,
                          int* __restrict__ deg, unsigned short* __restrict__ csrc) {
    int part = blockIdx.x & (NPART - 1);
    int e = (blockIdx.x >> 3) * 256 + threadIdx.x;
    if (e >= ETOT) return;
    int d, s;
    if (e < EE) { d = dstArr[e]; s = srcArr[e]; }
    else        { d = e - EE;    s = d; }
    d = min(max(d, 0), NN - 1);
    s = min(max(s, 0), NN - 1);
    int lo = part * DPP;
    if (d >= lo && d < lo + DPP) {
        int p = atomicAdd(&deg[d], 1);
        if (p < CAP) csrc[d * CAP + p] = (unsigned short)s;
    }
}

// ---------------- Layer 1 GEMM via MFMA: 32 nodes/block; h1 SLICE-MAJOR ----------
// h1s[slice][node][32 cols] bf16: a gather slice is a compact 3.2MB region
// (fits one XCD's 4MB L2), no 128B-line straddle into other slices.
__global__ __launch_bounds__(256, 2)
void k_gemm1(const float* __restrict__ x, const bf16* __restrict__ wt1,
             const float* __restrict__ aw_s, const float* __restrict__ aw_d,
             bf16* __restrict__ h1s, float* __restrict__ as1,
             float* __restrict__ ad1) {
    int n0 = blockIdx.x * 32;
    int t = threadIdx.x;
    __shared__ bf16 xs[32 * 136];
    for (int i = 0; i < 4; i++) {
        int idx = t + 256 * i;
        int r = idx >> 5, c4 = idx & 31;
        float4 v = make_float4(0.f, 0.f, 0.f, 0.f);
        if (n0 + r < NN) v = *(const float4*)(x + (size_t)(n0 + r) * 128 + c4 * 4);
        ushort4 o;
        o.x = f2bfbits(v.x); o.y = f2bfbits(v.y);
        o.z = f2bfbits(v.z); o.w = f2bfbits(v.w);
        *(ushort4*)(&xs[r * 136 + c4 * 4]) = o;
    }
    __syncthreads();

    int wv = t >> 6, lane = t & 63;
    int q = lane >> 4, r16 = lane & 15;
    int rowBase = (wv & 1) * 16;
    int colBase = (wv >> 1) * 128;

    f32x4 acc[8];
#pragma unroll
    for (int ct = 0; ct < 8; ct++) acc[ct] = (f32x4){0.f, 0.f, 0.f, 0.f};

#pragma unroll
    for (int kt = 0; kt < 4; kt++) {
        v8bf va = *(const v8bf*)(&xs[(rowBase + r16) * 136 + kt * 32 + q * 8]);
#pragma unroll
        for (int ct = 0; ct < 8; ct++) {
            v8bf vb = *(const v8bf*)(wt1 + (size_t)(colBase + ct * 16 + r16) * 128 + kt * 32 + q * 8);
            acc[ct] = __builtin_amdgcn_mfma_f32_16x16x32_bf16(va, vb, acc[ct], 0, 0, 0);
        }
    }

    float wsv[8], wdv[8];
#pragma unroll
    for (int ct = 0; ct < 8; ct++) {
        int col = colBase + ct * 16 + r16;
        wsv[ct] = aw_s[col];
        wdv[ct] = aw_d[col];
    }

    float ps[4][2], pd[4][2];
#pragma unroll
    for (int reg = 0; reg < 4; reg++) {
        ps[reg][0] = 0.f; ps[reg][1] = 0.f;
        pd[reg][0] = 0.f; pd[reg][1] = 0.f;
    }

#pragma unroll
    for (int reg = 0; reg < 4; reg++) {
        int node = n0 + rowBase + q * 4 + reg;
        bool ok = node < NN;
#pragma unroll
        for (int ct = 0; ct < 8; ct++) {
            float v = acc[ct][reg];
            int col = colBase + ct * 16 + r16;
            if (ok) h1s[((size_t)(col >> 5) * NN + node) * 32 + (col & 31)] = __float2bfloat16(v);
            ps[reg][ct >> 2] += v * wsv[ct];
            pd[reg][ct >> 2] += v * wdv[ct];
        }
    }

#pragma unroll
    for (int reg = 0; reg < 4; reg++) {
        int node = n0 + rowBase + q * 4 + reg;
        bool ok = node < NN;
#pragma unroll
        for (int lh = 0; lh < 2; lh++) {
            float a = ps[reg][lh], b = pd[reg][lh];
            for (int mask = 1; mask <= 8; mask <<= 1) {
                a += __shfl_xor(a, mask);
                b += __shfl_xor(b, mask);
            }
            if (r16 == 0 && ok) {
                int head = (wv >> 1) * 2 + lh;
                as1[node * 4 + head] = a;
                ad1[node * 4 + head] = b;
            }
        }
    }
}

// ---------------- edge-weight precompute L1: pw1[head][n][j] = (src<<16)|bf16(w) ----
// nt stores: the 51MB producer stream must not evict the h1s slices from L2.
__global__ __launch_bounds__(256, 8)
void k_edgew1(const unsigned short* __restrict__ csrc, const int* __restrict__ deg,
              const float* __restrict__ as1, const float* __restrict__ ad1,
              unsigned int* __restrict__ pw1) {
    int wv = threadIdx.x >> 6;
    int n = blockIdx.x * 4 + wv;        // NN % 4 == 0
    int l = threadIdx.x & 63;
    int cnt = min(deg[n], CAP);
    if (l >= cnt) return;
    int s = (int)csrc[(size_t)n * CAP + l];
    float4 as = *(const float4*)&as1[s * 4];
    float4 ad = *(const float4*)&ad1[n * 4];
    unsigned int sb = (unsigned int)s << 16;
    size_t o = (size_t)n * CAP + l;
    __builtin_nontemporal_store(sb | f2bfbits(lrelu_exp(as.x + ad.x)), pw1 + 0 * NC + o);
    __builtin_nontemporal_store(sb | f2bfbits(lrelu_exp(as.y + ad.y)), pw1 + 1 * NC + o);
    __builtin_nontemporal_store(sb | f2bfbits(lrelu_exp(as.z + ad.z)), pw1 + 2 * NC + o);
    __builtin_nontemporal_store(sb | f2bfbits(lrelu_exp(as.w + ad.w)), pw1 + 3 * NC + o);
}

// ---------------- Layer 1 gather: slice-per-XCD + 8-deep MLP + pipelined pw.
// slice = blockIdx&7 -> one XCD; h1s slice (3.2MB) is L2-resident (R5: FETCH 69MB).
// 16 lanes = one node's 32-col slice; 4 nodes/wave. pw batch for the NEXT 8 edges
// is prefetched (cached loads) while the current 8 gathers are in flight:
// dep chain per 8 edges ~= one L2 hit, 8 gather loads outstanding per subgroup.
__global__ __launch_bounds__(256, 6)
void k_gather1(const unsigned int* __restrict__ pw1, const int* __restrict__ deg,
               const bf16* __restrict__ h1s, const float* __restrict__ b1,
               bf16* __restrict__ x2) {
    int slice = blockIdx.x & 7;
    int ng = blockIdx.x >> 3;            // 0..3124
    int t = threadIdx.x;
    int sub = t >> 4;                    // node subgroup 0..15
    int c = t & 15;                      // column-pair within slice
    int n = ng * 16 + sub;               // NN % 16 == 0
    int head = slice >> 1;
    int cnt = min(deg[n], CAP);
    const unsigned int* base = pw1 + (size_t)head * NC + (size_t)n * CAP;
    const char* hsc = (const char*)h1s;
    unsigned int tconst = (unsigned int)slice * (NN * 64) + (unsigned int)c * 4;
    float a0 = 0.f, a1 = 0.f, ssum = 0.f;
    uint4 pa = *(const uint4*)(base);        // edges 0..3 (region always 64 slots)
    uint4 pb = *(const uint4*)(base + 4);    // edges 4..7
    int j = 0;
    for (; j + 7 < cnt; j += 8) {
        uint4 ca = pa, cb = pb;
        pa = *(const uint4*)(base + j + 8);   // prefetch next batch (padded alloc)
        pb = *(const uint4*)(base + j + 12);
        unsigned int o0 = ((ca.x & 0xffff0000u) >> 10) + tconst;  // (src<<6)+tconst
        unsigned int o1 = ((ca.y & 0xffff0000u) >> 10) + tconst;
        unsigned int o2 = ((ca.z & 0xffff0000u) >> 10) + tconst;
        unsigned int o3 = ((ca.w & 0xffff0000u) >> 10) + tconst;
        unsigned int o4 = ((cb.x & 0xffff0000u) >> 10) + tconst;
        unsigned int o5 = ((cb.y & 0xffff0000u) >> 10) + tconst;
        unsigned int o6 = ((cb.z & 0xffff0000u) >> 10) + tconst;
        unsigned int o7 = ((cb.w & 0xffff0000u) >> 10) + tconst;
        unsigned int u0 = *(const unsigned int*)(hsc + o0);
        unsigned int u1 = *(const unsigned int*)(hsc + o1);
        unsigned int u2 = *(const unsigned int*)(hsc + o2);
        unsigned int u3 = *(const unsigned int*)(hsc + o3);
        unsigned int u4 = *(const unsigned int*)(hsc + o4);
        unsigned int u5 = *(const unsigned int*)(hsc + o5);
        unsigned int u6 = *(const unsigned int*)(hsc + o6);
        unsigned int u7 = *(const unsigned int*)(hsc + o7);
        float w0 = us2f((unsigned short)(ca.x & 0xffffu));
        float w1 = us2f((unsigned short)(ca.y & 0xffffu));
        float w2 = us2f((unsigned short)(ca.z & 0xffffu));
        float w3 = us2f((unsigned short)(ca.w & 0xffffu));
        float w4 = us2f((unsigned short)(cb.x & 0xffffu));
        float w5 = us2f((unsigned short)(cb.y & 0xffffu));
        float w6 = us2f((unsigned short)(cb.z & 0xffffu));
        float w7 = us2f((unsigned short)(cb.w & 0xffffu));
        ssum += (w0 + w1) + (w2 + w3) + (w4 + w5) + (w6 + w7);
        a0 = fmaf(w0, lo2f(u0), a0); a1 = fmaf(w0, hi2f(u0), a1);
        a0 = fmaf(w1, lo2f(u1), a0); a1 = fmaf(w1, hi2f(u1), a1);
        a0 = fmaf(w2, lo2f(u2), a0); a1 = fmaf(w2, hi2f(u2), a1);
        a0 = fmaf(w3, lo2f(u3), a0); a1 = fmaf(w3, hi2f(u3), a1);
        a0 = fmaf(w4, lo2f(u4), a0); a1 = fmaf(w4, hi2f(u4), a1);
        a0 = fmaf(w5, lo2f(u5), a0); a1 = fmaf(w5, hi2f(u5), a1);
        a0 = fmaf(w6, lo2f(u6), a0); a1 = fmaf(w6, hi2f(u6), a1);
        a0 = fmaf(w7, lo2f(u7), a0); a1 = fmaf(w7, hi2f(u7), a1);
    }
    int r = cnt - j;   // 0..7 remaining, already in pa/pb
#pragma unroll
    for (int k = 0; k < 8; k++) {
        if (k < r) {
            unsigned int p = k == 0 ? pa.x : k == 1 ? pa.y : k == 2 ? pa.z : k == 3 ? pa.w
                           : k == 4 ? pb.x : k == 5 ? pb.y : k == 6 ? pb.z : pb.w;
            unsigned int o = ((p & 0xffff0000u) >> 10) + tconst;
            float wq = us2f((unsigned short)(p & 0xffffu));
            unsigned int u = *(const unsigned int*)(hsc + o);
            ssum += wq;
            a0 = fmaf(wq, lo2f(u), a0); a1 = fmaf(wq, hi2f(u), a1);
        }
    }
    float inv = 1.f / fmaxf(ssum, 1e-35f);
    int col = slice * 32 + c * 2;
    float2 bv = *(const float2*)&b1[col];
    float r0 = a0 * inv + bv.x;
    float r1 = a1 * inv + bv.y;
    r0 = r0 > 0.f ? r0 : (__expf(r0) - 1.f);
    r1 = r1 > 0.f ? r1 : (__expf(r1) - 1.f);
    unsigned int packed = (unsigned int)f2bfbits(r0) | ((unsigned int)f2bfbits(r1) << 16);
    *(unsigned int*)((unsigned short*)x2 + (size_t)n * 256 + col) = packed;  // cached: gemm2 reads next
}

// ---------------- Layer 2 GEMM via MFMA: 32 nodes/block; h2 SLICE-MAJOR [4][N][32] ----
__global__ __launch_bounds__(256, 2)
void k_gemm2(const bf16* __restrict__ x2, const bf16* __restrict__ wt2,
             const float* __restrict__ aw_s, const float* __restrict__ aw_d,
             bf16* __restrict__ h2s, float* __restrict__ as2,
             float* __restrict__ ad2) {
    int n0 = blockIdx.x * 32;
    int t = threadIdx.x;
    __shared__ bf16 xs[32 * 264];
    __shared__ float psPart[32][2];
    __shared__ float pdPart[32][2];
    for (int i = 0; i < 4; i++) {
        int idx = t + 256 * i;
        int r = idx >> 5, c8 = idx & 31;
        uint4 v;
        if (n0 + r < NN) v = *(const uint4*)(x2 + (size_t)(n0 + r) * 256 + c8 * 8);
        else             v = make_uint4(0, 0, 0, 0);
        *(uint4*)(&xs[r * 264 + c8 * 8]) = v;
    }
    __syncthreads();

    int wv = t >> 6, lane = t & 63;
    int q = lane >> 4, r16 = lane & 15;
    int rowBase = (wv & 1) * 16;
    int colBase = (wv >> 1) * 64;

    f32x4 acc[4];
#pragma unroll
    for (int ct = 0; ct < 4; ct++) acc[ct] = (f32x4){0.f, 0.f, 0.f, 0.f};

#pragma unroll
    for (int kt = 0; kt < 8; kt++) {
        v8bf va = *(const v8bf*)(&xs[(rowBase + r16) * 264 + kt * 32 + q * 8]);
#pragma unroll
        for (int ct = 0; ct < 4; ct++) {
            v8bf vb = *(const v8bf*)(wt2 + (size_t)(colBase + ct * 16 + r16) * 256 + kt * 32 + q * 8);
            acc[ct] = __builtin_amdgcn_mfma_f32_16x16x32_bf16(va, vb, acc[ct], 0, 0, 0);
        }
    }

    float wsv[4], wdv[4];
#pragma unroll
    for (int ct = 0; ct < 4; ct++) {
        int col = colBase + ct * 16 + r16;
        wsv[ct] = aw_s[col];
        wdv[ct] = aw_d[col];
    }

#pragma unroll
    for (int reg = 0; reg < 4; reg++) {
        int node = n0 + rowBase + q * 4 + reg;
        bool ok = node < NN;
        float ps = 0.f, pd = 0.f;
#pragma unroll
        for (int ct = 0; ct < 4; ct++) {
            float v = acc[ct][reg];
            int col = colBase + ct * 16 + r16;
            if (ok) h2s[((size_t)(col >> 5) * NN + node) * 32 + (col & 31)] = __float2bfloat16(v);
            ps += v * wsv[ct];
            pd += v * wdv[ct];
        }
        for (int mask = 1; mask <= 8; mask <<= 1) {
            ps += __shfl_xor(ps, mask);
            pd += __shfl_xor(pd, mask);
        }
        if (r16 == 0) {
            int li = rowBase + q * 4 + reg;
            psPart[li][wv >> 1] = ps;
            pdPart[li][wv >> 1] = pd;
        }
    }
    __syncthreads();
    if (t < 32) {
        int node = n0 + t;
        if (node < NN) {
            as2[node] = psPart[t][0] + psPart[t][1];
            ad2[node] = pdPart[t][0] + pdPart[t][1];
        }
    }
}

// ---------------- edge-weight precompute L2 (single head) ----------------
__global__ __launch_bounds__(256, 8)
void k_edgew2(const unsigned short* __restrict__ csrc, const int* __restrict__ deg,
              const float* __restrict__ as2, const float* __restrict__ ad2,
              unsigned int* __restrict__ pw2) {
    int wv = threadIdx.x >> 6;
    int n = blockIdx.x * 4 + wv;
    int l = threadIdx.x & 63;
    int cnt = min(deg[n], CAP);
    if (l >= cnt) return;
    int s = (int)csrc[(size_t)n * CAP + l];
    float w = lrelu_exp(as2[s] + ad2[n]);
    __builtin_nontemporal_store(((unsigned int)s << 16) | f2bfbits(w),
                                pw2 + (size_t)n * CAP + l);
}

// ---------------- Layer 2 gather: 4 slices of h2s, same 8-deep pipelined structure ----
__global__ __launch_bounds__(256, 6)
void k_gather2(const unsigned int* __restrict__ pw2, const int* __restrict__ deg,
               const bf16* __restrict__ h2s, const float* __restrict__ b2,
               bf16* __restrict__ hf) {
    int slice = blockIdx.x & 3;
    int ng = blockIdx.x >> 2;            // 0..3124
    int t = threadIdx.x;
    int sub = t >> 4;
    int c = t & 15;
    int n = ng * 16 + sub;
    int cnt = min(deg[n], CAP);
    const unsigned int* base = pw2 + (size_t)n * CAP;
    const char* hsc = (const char*)h2s;
    unsigned int tconst = (unsigned int)slice * (NN * 64) + (unsigned int)c * 4;
    float a0 = 0.f, a1 = 0.f, ssum = 0.f;
    uint4 pa = *(const uint4*)(base);
    uint4 pb = *(const uint4*)(base + 4);
    int j = 0;
    for (; j + 7 < cnt; j += 8) {
        uint4 ca = pa, cb = pb;
        pa = *(const uint4*)(base + j + 8);
        pb = *(const uint4*)(base + j + 12);
        unsigned int o0 = ((ca.x & 0xffff0000u) >> 10) + tconst;
        unsigned int o1 = ((ca.y & 0xffff0000u) >> 10) + tconst;
        unsigned int o2 = ((ca.z & 0xffff0000u) >> 10) + tconst;
        unsigned int o3 = ((ca.w & 0xffff0000u) >> 10) + tconst;
        unsigned int o4 = ((cb.x & 0xffff0000u) >> 10) + tconst;
        unsigned int o5 = ((cb.y & 0xffff0000u) >> 10) + tconst;
        unsigned int o6 = ((cb.z & 0xffff0000u) >> 10) + tconst;
        unsigned int o7 = ((cb.w & 0xffff0000u) >> 10) + tconst;
        unsigned int u0 = *(const unsigned int*)(hsc + o0);
        unsigned int u1 = *(const unsigned int*)(hsc + o1);
        unsigned int u2 = *(const unsigned int*)(hsc + o2);
        unsigned int u3 = *(const unsigned int*)(hsc + o3);
        unsigned int u4 = *(const unsigned int*)(hsc + o4);
        unsigned int u5 = *(const unsigned int*)(hsc + o5);
        unsigned int u6 = *(const unsigned int*)(hsc + o6);
        unsigned int u7 = *(const unsigned int*)(hsc + o7);
        float w0 = us2f((unsigned short)(ca.x & 0xffffu));
        float w1 = us2f((unsigned short)(ca.y & 0xffffu));
        float w2 = us2f((unsigned short)(ca.z & 0xffffu));
        float w3 = us2f((unsigned short)(ca.w & 0xffffu));
        float w4 = us2f((unsigned short)(cb.x & 0xffffu));
        float w5 = us2f((unsigned short)(cb.y & 0xffffu));
        float w6 = us2f((unsigned short)(cb.z & 0xffffu));
        float w7 = us2f((unsigned short)(cb.w & 0xffffu));
        ssum += (w0 + w1) + (w2 + w3) + (w4 + w5) + (w6 + w7);
        a0 = fmaf(w0, lo2f(u0), a0); a1 = fmaf(w0, hi2f(u0), a1);
        a0 = fmaf(w1, lo2f(u1), a0); a1 = fmaf(w1, hi2f(u1), a1);
        a0 = fmaf(w2, lo2f(u2), a0); a1 = fmaf(w2, hi2f(u2), a1);
        a0 = fmaf(w3, lo2f(u3), a0); a1 = fmaf(w3, hi2f(u3), a1);
        a0 = fmaf(w4, lo2f(u4), a0); a1 = fmaf(w4, hi2f(u4), a1);
        a0 = fmaf(w5, lo2f(u5), a0); a1 = fmaf(w5, hi2f(u5), a1);
        a0 = fmaf(w6, lo2f(u6), a0); a1 = fmaf(w6, hi2f(u6), a1);
        a0 = fmaf(w7, lo2f(u7), a0); a1 = fmaf(w7, hi2f(u7), a1);
    }
    int r = cnt - j;
#pragma unroll
    for (int k = 0; k < 8; k++) {
        if (k < r) {
            unsigned int p = k == 0 ? pa.x : k == 1 ? pa.y : k == 2 ? pa.z : k == 3 ? pa.w
                           : k == 4 ? pb.x : k == 5 ? pb.y : k == 6 ? pb.z : pb.w;
            unsigned int o = ((p & 0xffff0000u) >> 10) + tconst;
            float wq = us2f((unsigned short)(p & 0xffffu));
            unsigned int u = *(const unsigned int*)(hsc + o);
            ssum += wq;
            a0 = fmaf(wq, lo2f(u), a0); a1 = fmaf(wq, hi2f(u), a1);
        }
    }
    float inv = 1.f / fmaxf(ssum, 1e-35f);
    int col = slice * 32 + c * 2;
    float2 bv = *(const float2*)&b2[col];
    float r0 = a0 * inv + bv.x;
    float r1 = a1 * inv + bv.y;
    r0 = r0 > 0.f ? r0 : (__expf(r0) - 1.f);
    r1 = r1 > 0.f ? r1 : (__expf(r1) - 1.f);
    unsigned int packed = (unsigned int)f2bfbits(r0) | ((unsigned int)f2bfbits(r1) << 16);
    *(unsigned int*)((unsigned short*)hf + (size_t)n * 128 + col) = packed;  // cached: k_pool reads
}

// ---------------- fused mean-pool + linear + sigmoid (batch SORTED; bf16 input) ----------------
__global__ void k_pool(const bf16* __restrict__ hf, const int* __restrict__ batch,
                       const float* __restrict__ Wl, const float* __restrict__ bl,
                       float* __restrict__ out) {
    int b = blockIdx.x;   // 0..511
    int t = threadIdx.x;  // 0..127
    int lo = 0, hi = NN;
    while (lo < hi) { int m = (lo + hi) >> 1; if (batch[m] < b) lo = m + 1; else hi = m; }
    int start = lo;
    int lo2 = start, hi2 = NN;
    while (lo2 < hi2) { int m = (lo2 + hi2) >> 1; if (batch[m] < b + 1) lo2 = m + 1; else hi2 = m; }
    int end = lo2;
    const unsigned short* hu = (const unsigned short*)hf;
    float sum = 0.f;
    for (int n = start; n < end; n++) sum += us2f(hu[(size_t)n * 128 + t]);
    int c = end - start;
    float g = sum / (float)(c > 0 ? c : 1);
    float p = g * Wl[t];
    for (int o = 32; o > 0; o >>= 1) p += __shfl_down(p, o);
    __shared__ float red[2];
    if ((t & 63) == 0) red[t >> 6] = p;
    __syncthreads();
    if (t == 0) {
        float acc = red[0] + red[1] + bl[0];
        out[b] = 1.f / (1.f + __expf(-acc));
    }
}

extern "C" void kernel_launch(void* const* d_in, const int* in_sizes, int n_in,
                              void* d_out, int out_size, void* d_ws, size_t ws_size,
                              hipStream_t stream) {
    const float* x = (const float*)d_in[0];
    const int* ei = (const int*)d_in[1];
    const int* batch = (const int*)d_in[2];
    const float* W1 = (const float*)d_in[3];
    const float* aw_s1 = (const float*)d_in[4];
    const float* aw_d1 = (const float*)d_in[5];
    const float* b1 = (const float*)d_in[6];
    const float* W2 = (const float*)d_in[7];
    const float* aw_s2 = (const float*)d_in[8];
    const float* aw_d2 = (const float*)d_in[9];
    const float* b2 = (const float*)d_in[10];
    const float* Wl = (const float*)d_in[11];
    const float* bl = (const float*)d_in[12];
    const int* srcArr = ei;
    const int* dstArr = ei + EE;

    char* w = (char*)d_ws;
    size_t off = 0;
    auto alloc = [&](size_t bytes) -> void* {
        void* p = (void*)(w + off);
        off = (off + bytes + 255) & ~(size_t)255;
        return p;
    };
    bf16* bufA = (bf16*)alloc((size_t)NN * 256 * 2);   // h1s [8][N][32]; later h2s [4][N][32]
    bf16* bufB = (bf16*)alloc((size_t)NN * 256 * 2);   // x2 [N][256]; later hf [N][128]
    unsigned short* csrc = (unsigned short*)alloc(NC * 2);       // 6.4 MB
    unsigned int* pw1 = (unsigned int*)alloc(4 * NC * 4 + 64);   // 51.2 MB (+prefetch pad)
    unsigned int* pw2 = (unsigned int*)alloc(NC * 4 + 64);       // 12.8 MB (+pad)
    float* as1 = (float*)alloc((size_t)NN * 4 * 4);
    float* ad1 = (float*)alloc((size_t)NN * 4 * 4);
    float* as2 = (float*)alloc((size_t)NN * 4);
    float* ad2 = (float*)alloc((size_t)NN * 4);
    int* deg = (int*)alloc((size_t)NN * 4);
    bf16* wt1 = (bf16*)alloc((size_t)256 * 128 * 2);
    bf16* wt2 = (bf16*)alloc((size_t)128 * 256 * 2);
    (void)ws_size;

    k_prep<<<256, 256, 0, stream>>>(W1, W2, wt1, wt2, deg);
    int chunks = (ETOT + 255) / 256;
    k_scatter<<<chunks * NPART, 256, 0, stream>>>(srcArr, dstArr, deg, csrc);

    bf16* h1s = bufA;
    bf16* x2 = bufB;
    k_gemm1<<<(NN + 31) / 32, 256, 0, stream>>>(x, wt1, aw_s1, aw_d1, h1s, as1, ad1);
    k_edgew1<<<NN / 4, 256, 0, stream>>>(csrc, deg, as1, ad1, pw1);
    k_gather1<<<(NN / 16) * 8, 256, 0, stream>>>(pw1, deg, h1s, b1, x2);

    bf16* h2s = bufA;  // h1s dead after gather1
    k_gemm2<<<(NN + 31) / 32, 256, 0, stream>>>(x2, wt2, aw_s2, aw_d2, h2s, as2, ad2);
    k_edgew2<<<NN / 4, 256, 0, stream>>>(csrc, deg, as2, ad2, pw2);

    bf16* hf = bufB;   // x2 dead after gemm2
    k_gather2<<<(NN / 16) * 4, 256, 0, stream>>>(pw2, deg, h2s, b2, hf);

    k_pool<<<BB, 128, 0, stream>>>(hf, batch, Wl, bl, (float*)d_out);
}

// Round 7
// 329.422 us; speedup vs baseline: 1.5380x; 1.1088x over previous
//
#include <hip/hip_runtime.h>
#include <hip/hip_bf16.h>

#define NN 50000
#define EE 800000
#define ETOT 850000
#define BB 512
#define CAP 64     // bucket capacity per node; Poisson(17) => P(deg>63) ~ 1e-18
#define NPART 8    // dst-range partitions (one per XCD under round-robin dispatch)
#define DPP 6250   // nodes per partition = NN/NPART
#define SCAT_BLKS 2048   // scatter portion of the fused scatter||gemm1 launch

typedef __hip_bfloat16 bf16;
typedef __attribute__((ext_vector_type(8))) __bf16 v8bf;
typedef __attribute__((ext_vector_type(4))) float f32x4;

__device__ __forceinline__ float lo2f(unsigned int u) {
    return __uint_as_float(u << 16);
}
__device__ __forceinline__ float hi2f(unsigned int u) {
    return __uint_as_float(u & 0xffff0000u);
}
__device__ __forceinline__ float us2f(unsigned short u) {
    return __uint_as_float(((unsigned int)u) << 16);
}
__device__ __forceinline__ unsigned short f2bfbits(float f) {
    bf16 h = __float2bfloat16(f);
    return *reinterpret_cast<unsigned short*>(&h);
}
__device__ __forceinline__ float lrelu_exp(float ev) {
    ev = ev > 0.f ? ev : 0.2f * ev;
    return __expf(fminf(ev, 80.f));
}

// ---------------- prep: weight transpose+cvt AND zero deg ----------------
__global__ void k_prep(const float* __restrict__ W1, const float* __restrict__ W2,
                       bf16* __restrict__ wt1, bf16* __restrict__ wt2,
                       int* __restrict__ deg) {
    int idx = blockIdx.x * blockDim.x + threadIdx.x;  // 65536 threads
    if (idx < 256 * 128) {
        int c = idx >> 7, k = idx & 127;
        wt1[idx] = __float2bfloat16(W1[k * 256 + c]);
    } else {
        int j = idx - 256 * 128;
        int c = j >> 8, k = j & 255;
        wt2[j] = __float2bfloat16(W2[k * 128 + c]);
    }
    if (idx < NN) deg[idx] = 0;
}

// ---------------- FUSED: XCD-partitioned scatter (blocks 0..SCAT_BLKS-1, grid-strided)
//                  || Layer-1 GEMM via MFMA (remaining blocks, proven R12 body).
// scatter and gemm1 have no data dependence; fusing one launch overlaps them on the
// machine instead of serializing on the stream.
__global__ __launch_bounds__(256, 2)
void k_scatter_gemm1(const int* __restrict__ srcArr, const int* __restrict__ dstArr,
                     int* __restrict__ deg, unsigned short* __restrict__ csrc,
                     const float* __restrict__ x, const bf16* __restrict__ wt1,
                     const float* __restrict__ aw_s, const float* __restrict__ aw_d,
                     bf16* __restrict__ h1, float* __restrict__ as1,
                     float* __restrict__ ad1) {
    __shared__ bf16 xs[32 * 136];
    if (blockIdx.x < SCAT_BLKS) {
        // ---- scatter: part = blockIdx&7 -> one XCD; dst range stays XCD-local ----
        int part = blockIdx.x & (NPART - 1);
        int lo = part * DPP;
        int t = threadIdx.x;
        const int STRIDE = (SCAT_BLKS >> 3) * 256;   // 65536
        for (int e = (blockIdx.x >> 3) * 256 + t; e < ETOT; e += STRIDE) {
            int d, s;
            if (e < EE) { d = dstArr[e]; s = srcArr[e]; }
            else        { d = e - EE;    s = d; }
            d = min(max(d, 0), NN - 1);
            s = min(max(s, 0), NN - 1);
            if (d >= lo && d < lo + DPP) {
                int p = atomicAdd(&deg[d], 1);
                if (p < CAP) csrc[d * CAP + p] = (unsigned short)s;
            }
        }
        return;
    }

    // ---- gemm1: 32 nodes/block, h1 row-major [N][256] ----
    int bid = blockIdx.x - SCAT_BLKS;
    int n0 = bid * 32;
    int t = threadIdx.x;
    for (int i = 0; i < 4; i++) {
        int idx = t + 256 * i;
        int r = idx >> 5, c4 = idx & 31;
        float4 v = make_float4(0.f, 0.f, 0.f, 0.f);
        if (n0 + r < NN) v = *(const float4*)(x + (size_t)(n0 + r) * 128 + c4 * 4);
        ushort4 o;
        o.x = f2bfbits(v.x); o.y = f2bfbits(v.y);
        o.z = f2bfbits(v.z); o.w = f2bfbits(v.w);
        *(ushort4*)(&xs[r * 136 + c4 * 4]) = o;
    }
    __syncthreads();

    int wv = t >> 6, lane = t & 63;
    int q = lane >> 4, r16 = lane & 15;
    int rowBase = (wv & 1) * 16;
    int colBase = (wv >> 1) * 128;

    f32x4 acc[8];
#pragma unroll
    for (int ct = 0; ct < 8; ct++) acc[ct] = (f32x4){0.f, 0.f, 0.f, 0.f};

#pragma unroll
    for (int kt = 0; kt < 4; kt++) {
        v8bf va = *(const v8bf*)(&xs[(rowBase + r16) * 136 + kt * 32 + q * 8]);
#pragma unroll
        for (int ct = 0; ct < 8; ct++) {
            v8bf vb = *(const v8bf*)(wt1 + (size_t)(colBase + ct * 16 + r16) * 128 + kt * 32 + q * 8);
            acc[ct] = __builtin_amdgcn_mfma_f32_16x16x32_bf16(va, vb, acc[ct], 0, 0, 0);
        }
    }

    float wsv[8], wdv[8];
#pragma unroll
    for (int ct = 0; ct < 8; ct++) {
        int col = colBase + ct * 16 + r16;
        wsv[ct] = aw_s[col];
        wdv[ct] = aw_d[col];
    }

    float ps[4][2], pd[4][2];
#pragma unroll
    for (int reg = 0; reg < 4; reg++) {
        ps[reg][0] = 0.f; ps[reg][1] = 0.f;
        pd[reg][0] = 0.f; pd[reg][1] = 0.f;
    }

#pragma unroll
    for (int reg = 0; reg < 4; reg++) {
        int node = n0 + rowBase + q * 4 + reg;
        bool ok = node < NN;
#pragma unroll
        for (int ct = 0; ct < 8; ct++) {
            float v = acc[ct][reg];
            if (ok) h1[(size_t)node * 256 + colBase + ct * 16 + r16] = __float2bfloat16(v);
            ps[reg][ct >> 2] += v * wsv[ct];
            pd[reg][ct >> 2] += v * wdv[ct];
        }
    }

#pragma unroll
    for (int reg = 0; reg < 4; reg++) {
        int node = n0 + rowBase + q * 4 + reg;
        bool ok = node < NN;
#pragma unroll
        for (int lh = 0; lh < 2; lh++) {
            float a = ps[reg][lh], b = pd[reg][lh];
            for (int mask = 1; mask <= 8; mask <<= 1) {
                a += __shfl_xor(a, mask);
                b += __shfl_xor(b, mask);
            }
            if (r16 == 0 && ok) {
                int head = (wv >> 1) * 2 + lh;
                as1[node * 4 + head] = a;
                ad1[node * 4 + head] = b;
            }
        }
    }
}

// ---------------- Layer 1 gather: 2 col-slices/node, single chunk (R0-proven 62us) ----
__global__ void k_gather1(const unsigned short* __restrict__ csrc, const int* __restrict__ deg,
                          const bf16* __restrict__ h1, const float* __restrict__ as1,
                          const float* __restrict__ ad1, const float* __restrict__ b1,
                          bf16* __restrict__ x2) {
    int bid = blockIdx.x;
    int n = bid >> 1, slice = bid & 1;
    int t = threadIdx.x;        // 0..63
    int lh = t >> 5;            // local head (0/1)
    int cnt = min(deg[n], CAP);
    float2 ad = *(const float2*)&ad1[n * 4 + slice * 2];
    __shared__ unsigned int ls[CAP];   // pre-scaled byte offsets (s*512)
    __shared__ float la[CAP * 2];
    const char* h1c = (const char*)h1;
    unsigned int tconst = (unsigned int)(slice * 128 + t * 2) * 2;
    if (t < cnt) {
        int s = (int)csrc[n * CAP + t];
        ls[t] = (unsigned int)s << 9;
        float2 as = *(const float2*)&as1[s * 4 + slice * 2];
        la[t * 2 + 0] = lrelu_exp(as.x + ad.x);
        la[t * 2 + 1] = lrelu_exp(as.y + ad.y);
    }
    __syncthreads();
    float a0 = 0.f, a1 = 0.f, ssum = 0.f;
    int j = 0;
    for (; j + 3 < cnt; j += 4) {
        unsigned int o0 = ls[j] + tconst, o1 = ls[j + 1] + tconst;
        unsigned int o2 = ls[j + 2] + tconst, o3 = ls[j + 3] + tconst;
        float A0 = la[j * 2 + lh], A1 = la[j * 2 + 2 + lh];
        float A2 = la[j * 2 + 4 + lh], A3 = la[j * 2 + 6 + lh];
        unsigned int u0 = *(const unsigned int*)(h1c + o0);
        unsigned int u1 = *(const unsigned int*)(h1c + o1);
        unsigned int u2 = *(const unsigned int*)(h1c + o2);
        unsigned int u3 = *(const unsigned int*)(h1c + o3);
        ssum += (A0 + A1) + (A2 + A3);
        a0 = fmaf(A0, lo2f(u0), a0); a0 = fmaf(A1, lo2f(u1), a0);
        a0 = fmaf(A2, lo2f(u2), a0); a0 = fmaf(A3, lo2f(u3), a0);
        a1 = fmaf(A0, hi2f(u0), a1); a1 = fmaf(A1, hi2f(u1), a1);
        a1 = fmaf(A2, hi2f(u2), a1); a1 = fmaf(A3, hi2f(u3), a1);
    }
    for (; j < cnt; j++) {
        unsigned int o0 = ls[j] + tconst;
        float A0 = la[j * 2 + lh];
        unsigned int u0 = *(const unsigned int*)(h1c + o0);
        ssum += A0;
        a0 = fmaf(A0, lo2f(u0), a0);
        a1 = fmaf(A0, hi2f(u0), a1);
    }
    float inv = 1.f / fmaxf(ssum, 1e-35f);
    int c = slice * 128 + t * 2;
    float r0 = a0 * inv + b1[c + 0];
    float r1 = a1 * inv + b1[c + 1];
    r0 = r0 > 0.f ? r0 : (__expf(r0) - 1.f);
    r1 = r1 > 0.f ? r1 : (__expf(r1) - 1.f);
    unsigned int packed = (unsigned int)f2bfbits(r0) | ((unsigned int)f2bfbits(r1) << 16);
    *(unsigned int*)((unsigned short*)x2 + (size_t)n * 256 + c) = packed;
}

// ---------------- Layer 2 GEMM via MFMA: 32 nodes/block (R18-proven) ----------------
__global__ __launch_bounds__(256, 2)
void k_gemm2(const bf16* __restrict__ x2, const bf16* __restrict__ wt2,
             const float* __restrict__ aw_s, const float* __restrict__ aw_d,
             bf16* __restrict__ h2, float* __restrict__ as2,
             float* __restrict__ ad2) {
    int n0 = blockIdx.x * 32;
    int t = threadIdx.x;
    __shared__ bf16 xs[32 * 264];
    __shared__ float psPart[32][2];
    __shared__ float pdPart[32][2];
    for (int i = 0; i < 4; i++) {
        int idx = t + 256 * i;
        int r = idx >> 5, c8 = idx & 31;
        uint4 v;
        if (n0 + r < NN) v = *(const uint4*)(x2 + (size_t)(n0 + r) * 256 + c8 * 8);
        else             v = make_uint4(0, 0, 0, 0);
        *(uint4*)(&xs[r * 264 + c8 * 8]) = v;
    }
    __syncthreads();

    int wv = t >> 6, lane = t & 63;
    int q = lane >> 4, r16 = lane & 15;
    int rowBase = (wv & 1) * 16;
    int colBase = (wv >> 1) * 64;

    f32x4 acc[4];
#pragma unroll
    for (int ct = 0; ct < 4; ct++) acc[ct] = (f32x4){0.f, 0.f, 0.f, 0.f};

#pragma unroll
    for (int kt = 0; kt < 8; kt++) {
        v8bf va = *(const v8bf*)(&xs[(rowBase + r16) * 264 + kt * 32 + q * 8]);
#pragma unroll
        for (int ct = 0; ct < 4; ct++) {
            v8bf vb = *(const v8bf*)(wt2 + (size_t)(colBase + ct * 16 + r16) * 256 + kt * 32 + q * 8);
            acc[ct] = __builtin_amdgcn_mfma_f32_16x16x32_bf16(va, vb, acc[ct], 0, 0, 0);
        }
    }

    float wsv[4], wdv[4];
#pragma unroll
    for (int ct = 0; ct < 4; ct++) {
        int col = colBase + ct * 16 + r16;
        wsv[ct] = aw_s[col];
        wdv[ct] = aw_d[col];
    }

#pragma unroll
    for (int reg = 0; reg < 4; reg++) {
        int node = n0 + rowBase + q * 4 + reg;
        bool ok = node < NN;
        float ps = 0.f, pd = 0.f;
#pragma unroll
        for (int ct = 0; ct < 4; ct++) {
            float v = acc[ct][reg];
            if (ok) h2[(size_t)node * 128 + colBase + ct * 16 + r16] = __float2bfloat16(v);
            ps += v * wsv[ct];
            pd += v * wdv[ct];
        }
        for (int mask = 1; mask <= 8; mask <<= 1) {
            ps += __shfl_xor(ps, mask);
            pd += __shfl_xor(pd, mask);
        }
        if (r16 == 0) {
            int li = rowBase + q * 4 + reg;
            psPart[li][wv >> 1] = ps;
            pdPart[li][wv >> 1] = pd;
        }
    }
    __syncthreads();
    if (t < 32) {
        int node = n0 + t;
        if (node < NN) {
            as2[node] = psPart[t][0] + psPart[t][1];
            ad2[node] = pdPart[t][0] + pdPart[t][1];
        }
    }
}

// ---------------- Layer 2 gather: single chunk, 32-bit offsets (R0-proven) ----------
__global__ void k_gather2(const unsigned short* __restrict__ csrc, const int* __restrict__ deg,
                          const bf16* __restrict__ h2, const float* __restrict__ as2,
                          const float* __restrict__ ad2, const float* __restrict__ b2,
                          bf16* __restrict__ hf) {
    int n = blockIdx.x;
    int t = threadIdx.x;        // 0..63
    int cnt = min(deg[n], CAP);
    float adn = ad2[n];
    __shared__ unsigned int ls[CAP];   // pre-scaled byte offsets (s*256)
    __shared__ float la[CAP];
    const char* h2c = (const char*)h2;
    unsigned int tconst = (unsigned int)t * 4;
    if (t < cnt) {
        int s = (int)csrc[n * CAP + t];
        ls[t] = (unsigned int)s << 8;
        la[t] = lrelu_exp(as2[s] + adn);
    }
    __syncthreads();
    float a0 = 0.f, a1 = 0.f, ssum = 0.f;
    int j = 0;
    for (; j + 3 < cnt; j += 4) {
        unsigned int o0 = ls[j] + tconst, o1 = ls[j + 1] + tconst;
        unsigned int o2 = ls[j + 2] + tconst, o3 = ls[j + 3] + tconst;
        float A0 = la[j], A1 = la[j + 1], A2 = la[j + 2], A3 = la[j + 3];
        unsigned int u0 = *(const unsigned int*)(h2c + o0);
        unsigned int u1 = *(const unsigned int*)(h2c + o1);
        unsigned int u2 = *(const unsigned int*)(h2c + o2);
        unsigned int u3 = *(const unsigned int*)(h2c + o3);
        ssum += (A0 + A1) + (A2 + A3);
        a0 = fmaf(A0, lo2f(u0), a0); a0 = fmaf(A1, lo2f(u1), a0);
        a0 = fmaf(A2, lo2f(u2), a0); a0 = fmaf(A3, lo2f(u3), a0);
        a1 = fmaf(A0, hi2f(u0), a1); a1 = fmaf(A1, hi2f(u1), a1);
        a1 = fmaf(A2, hi2f(u2), a1); a1 = fmaf(A3, hi2f(u3), a1);
    }
    for (; j < cnt; j++) {
        unsigned int o0 = ls[j] + tconst;
        float A0 = la[j];
        unsigned int u0 = *(const unsigned int*)(h2c + o0);
        ssum += A0;
        a0 = fmaf(A0, lo2f(u0), a0);
        a1 = fmaf(A0, hi2f(u0), a1);
    }
    float inv = 1.f / fmaxf(ssum, 1e-35f);
    int c = t * 2;
    float r0 = a0 * inv + b2[c + 0];
    float r1 = a1 * inv + b2[c + 1];
    r0 = r0 > 0.f ? r0 : (__expf(r0) - 1.f);
    r1 = r1 > 0.f ? r1 : (__expf(r1) - 1.f);
    unsigned int packed = (unsigned int)f2bfbits(r0) | ((unsigned int)f2bfbits(r1) << 16);
    *(unsigned int*)((unsigned short*)hf + (size_t)n * 128 + c) = packed;
}

// ---------------- fused mean-pool + linear + sigmoid (batch SORTED; bf16 input) ----------------
__global__ void k_pool(const bf16* __restrict__ hf, const int* __restrict__ batch,
                       const float* __restrict__ Wl, const float* __restrict__ bl,
                       float* __restrict__ out) {
    int b = blockIdx.x;   // 0..511
    int t = threadIdx.x;  // 0..127
    int lo = 0, hi = NN;
    while (lo < hi) { int m = (lo + hi) >> 1; if (batch[m] < b) lo = m + 1; else hi = m; }
    int start = lo;
    int lo2 = start, hi2 = NN;
    while (lo2 < hi2) { int m = (lo2 + hi2) >> 1; if (batch[m] < b + 1) lo2 = m + 1; else hi2 = m; }
    int end = lo2;
    const unsigned short* hu = (const unsigned short*)hf;
    float sum = 0.f;
    for (int n = start; n < end; n++) sum += us2f(hu[(size_t)n * 128 + t]);
    int c = end - start;
    float g = sum / (float)(c > 0 ? c : 1);
    float p = g * Wl[t];
    for (int o = 32; o > 0; o >>= 1) p += __shfl_down(p, o);
    __shared__ float red[2];
    if ((t & 63) == 0) red[t >> 6] = p;
    __syncthreads();
    if (t == 0) {
        float acc = red[0] + red[1] + bl[0];
        out[b] = 1.f / (1.f + __expf(-acc));
    }
}

extern "C" void kernel_launch(void* const* d_in, const int* in_sizes, int n_in,
                              void* d_out, int out_size, void* d_ws, size_t ws_size,
                              hipStream_t stream) {
    const float* x = (const float*)d_in[0];
    const int* ei = (const int*)d_in[1];
    const int* batch = (const int*)d_in[2];
    const float* W1 = (const float*)d_in[3];
    const float* aw_s1 = (const float*)d_in[4];
    const float* aw_d1 = (const float*)d_in[5];
    const float* b1 = (const float*)d_in[6];
    const float* W2 = (const float*)d_in[7];
    const float* aw_s2 = (const float*)d_in[8];
    const float* aw_d2 = (const float*)d_in[9];
    const float* b2 = (const float*)d_in[10];
    const float* Wl = (const float*)d_in[11];
    const float* bl = (const float*)d_in[12];
    const int* srcArr = ei;
    const int* dstArr = ei + EE;

    char* w = (char*)d_ws;
    size_t off = 0;
    auto alloc = [&](size_t bytes) -> void* {
        void* p = (void*)(w + off);
        off = (off + bytes + 255) & ~(size_t)255;
        return p;
    };
    bf16* bufA = (bf16*)alloc((size_t)NN * 256 * 2);   // h1; later h2
    bf16* bufB = (bf16*)alloc((size_t)NN * 256 * 2);   // x2; later hf (bf16 [NN,128])
    unsigned short* csrc = (unsigned short*)alloc((size_t)NN * CAP * 2);  // 6.4 MB
    float* as1 = (float*)alloc((size_t)NN * 4 * 4);
    float* ad1 = (float*)alloc((size_t)NN * 4 * 4);
    float* as2 = (float*)alloc((size_t)NN * 4);
    float* ad2 = (float*)alloc((size_t)NN * 4);
    int* deg = (int*)alloc((size_t)NN * 4);
    bf16* wt1 = (bf16*)alloc((size_t)256 * 128 * 2);
    bf16* wt2 = (bf16*)alloc((size_t)128 * 256 * 2);
    (void)ws_size;

    k_prep<<<256, 256, 0, stream>>>(W1, W2, wt1, wt2, deg);

    bf16* h1 = bufA;
    bf16* x2 = bufB;
    // fused: scatter (2048 grid-strided blocks) || gemm1 (1563 blocks) — independent work
    int gemmBlocks = (NN + 31) / 32;
    k_scatter_gemm1<<<SCAT_BLKS + gemmBlocks, 256, 0, stream>>>(
        srcArr, dstArr, deg, csrc, x, wt1, aw_s1, aw_d1, h1, as1, ad1);

    k_gather1<<<NN * 2, 64, 0, stream>>>(csrc, deg, h1, as1, ad1, b1, x2);

    bf16* h2 = bufA;  // h1 dead after gather1
    k_gemm2<<<gemmBlocks, 256, 0, stream>>>(x2, wt2, aw_s2, aw_d2, h2, as2, ad2);

    bf16* hf = bufB;  // x2 dead after gemm2
    k_gather2<<<NN, 64, 0, stream>>>(csrc, deg, h2, as2, ad2, b2, hf);

    k_pool<<<BB, 128, 0, stream>>>(hf, batch, Wl, bl, (float*)d_out);
}

// Round 8
// 309.977 us; speedup vs baseline: 1.6345x; 1.0627x over previous
//
#include <hip/hip_runtime.h>
#include <hip/hip_bf16.h>

#define NN 50000
#define EE 800000
#define ETOT 850000
#define BB 512
#define CAP 64     // bucket capacity per node; Poisson(17) => P(deg>63) ~ 1e-18
#define SCAT_BLKS ((ETOT + 255) / 256)   // 3321 single-pass scatter blocks (1 edge/thread)

typedef __hip_bfloat16 bf16;
typedef __attribute__((ext_vector_type(8))) __bf16 v8bf;
typedef __attribute__((ext_vector_type(4))) float f32x4;

__device__ __forceinline__ float lo2f(unsigned int u) {
    return __uint_as_float(u << 16);
}
__device__ __forceinline__ float hi2f(unsigned int u) {
    return __uint_as_float(u & 0xffff0000u);
}
__device__ __forceinline__ float us2f(unsigned short u) {
    return __uint_as_float(((unsigned int)u) << 16);
}
__device__ __forceinline__ unsigned short f2bfbits(float f) {
    bf16 h = __float2bfloat16(f);
    return *reinterpret_cast<unsigned short*>(&h);
}
__device__ __forceinline__ float lrelu_exp(float ev) {
    ev = ev > 0.f ? ev : 0.2f * ev;
    return __expf(fminf(ev, 80.f));
}

// ---------------- prep: weight transpose+cvt, zero deg AND zero gsum ----------------
__global__ void k_prep(const float* __restrict__ W1, const float* __restrict__ W2,
                       bf16* __restrict__ wt1, bf16* __restrict__ wt2,
                       int* __restrict__ deg, float* __restrict__ gsum) {
    int idx = blockIdx.x * blockDim.x + threadIdx.x;  // 65536 threads
    if (idx < 256 * 128) {
        int c = idx >> 7, k = idx & 127;
        wt1[idx] = __float2bfloat16(W1[k * 256 + c]);
    } else {
        int j = idx - 256 * 128;
        int c = j >> 8, k = j & 255;
        wt2[j] = __float2bfloat16(W2[k * 128 + c]);
    }
    if (idx < NN) deg[idx] = 0;
    gsum[idx] = 0.f;                 // 512*128 == 65536 exactly
}

// ---------------- FUSED: single-pass scatter (blocks 0..SCAT_BLKS-1, 1 edge/thread)
//                  || Layer-1 GEMM via MFMA (remaining blocks, proven R12 body).
// R7 postmortem: partitioned scatter re-scanned all edges 8x and serialized ~13
// dependent edge chains per thread (82us, VALUBusy 7.6%). Single pass: 850K fully
// parallel atomic chains, edge list read once.
__global__ __launch_bounds__(256, 2)
void k_scatter_gemm1(const int* __restrict__ srcArr, const int* __restrict__ dstArr,
                     int* __restrict__ deg, unsigned short* __restrict__ csrc,
                     const float* __restrict__ x, const bf16* __restrict__ wt1,
                     const float* __restrict__ aw_s, const float* __restrict__ aw_d,
                     bf16* __restrict__ h1, float* __restrict__ as1,
                     float* __restrict__ ad1) {
    __shared__ bf16 xs[32 * 136];
    if (blockIdx.x < SCAT_BLKS) {
        int e = blockIdx.x * 256 + threadIdx.x;
        if (e < ETOT) {
            int d, s;
            if (e < EE) { d = dstArr[e]; s = srcArr[e]; }
            else        { d = e - EE;    s = d; }
            d = min(max(d, 0), NN - 1);
            s = min(max(s, 0), NN - 1);
            int p = atomicAdd(&deg[d], 1);
            if (p < CAP) csrc[d * CAP + p] = (unsigned short)s;
        }
        return;
    }

    // ---- gemm1: 32 nodes/block, h1 row-major [N][256] ----
    int bid = blockIdx.x - SCAT_BLKS;
    int n0 = bid * 32;
    int t = threadIdx.x;
    for (int i = 0; i < 4; i++) {
        int idx = t + 256 * i;
        int r = idx >> 5, c4 = idx & 31;
        float4 v = make_float4(0.f, 0.f, 0.f, 0.f);
        if (n0 + r < NN) v = *(const float4*)(x + (size_t)(n0 + r) * 128 + c4 * 4);
        ushort4 o;
        o.x = f2bfbits(v.x); o.y = f2bfbits(v.y);
        o.z = f2bfbits(v.z); o.w = f2bfbits(v.w);
        *(ushort4*)(&xs[r * 136 + c4 * 4]) = o;
    }
    __syncthreads();

    int wv = t >> 6, lane = t & 63;
    int q = lane >> 4, r16 = lane & 15;
    int rowBase = (wv & 1) * 16;
    int colBase = (wv >> 1) * 128;

    f32x4 acc[8];
#pragma unroll
    for (int ct = 0; ct < 8; ct++) acc[ct] = (f32x4){0.f, 0.f, 0.f, 0.f};

#pragma unroll
    for (int kt = 0; kt < 4; kt++) {
        v8bf va = *(const v8bf*)(&xs[(rowBase + r16) * 136 + kt * 32 + q * 8]);
#pragma unroll
        for (int ct = 0; ct < 8; ct++) {
            v8bf vb = *(const v8bf*)(wt1 + (size_t)(colBase + ct * 16 + r16) * 128 + kt * 32 + q * 8);
            acc[ct] = __builtin_amdgcn_mfma_f32_16x16x32_bf16(va, vb, acc[ct], 0, 0, 0);
        }
    }

    float wsv[8], wdv[8];
#pragma unroll
    for (int ct = 0; ct < 8; ct++) {
        int col = colBase + ct * 16 + r16;
        wsv[ct] = aw_s[col];
        wdv[ct] = aw_d[col];
    }

    float ps[4][2], pd[4][2];
#pragma unroll
    for (int reg = 0; reg < 4; reg++) {
        ps[reg][0] = 0.f; ps[reg][1] = 0.f;
        pd[reg][0] = 0.f; pd[reg][1] = 0.f;
    }

#pragma unroll
    for (int reg = 0; reg < 4; reg++) {
        int node = n0 + rowBase + q * 4 + reg;
        bool ok = node < NN;
#pragma unroll
        for (int ct = 0; ct < 8; ct++) {
            float v = acc[ct][reg];
            if (ok) h1[(size_t)node * 256 + colBase + ct * 16 + r16] = __float2bfloat16(v);
            ps[reg][ct >> 2] += v * wsv[ct];
            pd[reg][ct >> 2] += v * wdv[ct];
        }
    }

#pragma unroll
    for (int reg = 0; reg < 4; reg++) {
        int node = n0 + rowBase + q * 4 + reg;
        bool ok = node < NN;
#pragma unroll
        for (int lh = 0; lh < 2; lh++) {
            float a = ps[reg][lh], b = pd[reg][lh];
            for (int mask = 1; mask <= 8; mask <<= 1) {
                a += __shfl_xor(a, mask);
                b += __shfl_xor(b, mask);
            }
            if (r16 == 0 && ok) {
                int head = (wv >> 1) * 2 + lh;
                as1[node * 4 + head] = a;
                ad1[node * 4 + head] = b;
            }
        }
    }
}

// ---------------- Layer 1 gather: 2 col-slices/node, single chunk (R0-proven 62us) ----
__global__ void k_gather1(const unsigned short* __restrict__ csrc, const int* __restrict__ deg,
                          const bf16* __restrict__ h1, const float* __restrict__ as1,
                          const float* __restrict__ ad1, const float* __restrict__ b1,
                          bf16* __restrict__ x2) {
    int bid = blockIdx.x;
    int n = bid >> 1, slice = bid & 1;
    int t = threadIdx.x;        // 0..63
    int lh = t >> 5;            // local head (0/1)
    int cnt = min(deg[n], CAP);
    float2 ad = *(const float2*)&ad1[n * 4 + slice * 2];
    __shared__ unsigned int ls[CAP];   // pre-scaled byte offsets (s*512)
    __shared__ float la[CAP * 2];
    const char* h1c = (const char*)h1;
    unsigned int tconst = (unsigned int)(slice * 128 + t * 2) * 2;
    if (t < cnt) {
        int s = (int)csrc[n * CAP + t];
        ls[t] = (unsigned int)s << 9;
        float2 as = *(const float2*)&as1[s * 4 + slice * 2];
        la[t * 2 + 0] = lrelu_exp(as.x + ad.x);
        la[t * 2 + 1] = lrelu_exp(as.y + ad.y);
    }
    __syncthreads();
    float a0 = 0.f, a1 = 0.f, ssum = 0.f;
    int j = 0;
    for (; j + 3 < cnt; j += 4) {
        unsigned int o0 = ls[j] + tconst, o1 = ls[j + 1] + tconst;
        unsigned int o2 = ls[j + 2] + tconst, o3 = ls[j + 3] + tconst;
        float A0 = la[j * 2 + lh], A1 = la[j * 2 + 2 + lh];
        float A2 = la[j * 2 + 4 + lh], A3 = la[j * 2 + 6 + lh];
        unsigned int u0 = *(const unsigned int*)(h1c + o0);
        unsigned int u1 = *(const unsigned int*)(h1c + o1);
        unsigned int u2 = *(const unsigned int*)(h1c + o2);
        unsigned int u3 = *(const unsigned int*)(h1c + o3);
        ssum += (A0 + A1) + (A2 + A3);
        a0 = fmaf(A0, lo2f(u0), a0); a0 = fmaf(A1, lo2f(u1), a0);
        a0 = fmaf(A2, lo2f(u2), a0); a0 = fmaf(A3, lo2f(u3), a0);
        a1 = fmaf(A0, hi2f(u0), a1); a1 = fmaf(A1, hi2f(u1), a1);
        a1 = fmaf(A2, hi2f(u2), a1); a1 = fmaf(A3, hi2f(u3), a1);
    }
    for (; j < cnt; j++) {
        unsigned int o0 = ls[j] + tconst;
        float A0 = la[j * 2 + lh];
        unsigned int u0 = *(const unsigned int*)(h1c + o0);
        ssum += A0;
        a0 = fmaf(A0, lo2f(u0), a0);
        a1 = fmaf(A0, hi2f(u0), a1);
    }
    float inv = 1.f / fmaxf(ssum, 1e-35f);
    int c = slice * 128 + t * 2;
    float r0 = a0 * inv + b1[c + 0];
    float r1 = a1 * inv + b1[c + 1];
    r0 = r0 > 0.f ? r0 : (__expf(r0) - 1.f);
    r1 = r1 > 0.f ? r1 : (__expf(r1) - 1.f);
    unsigned int packed = (unsigned int)f2bfbits(r0) | ((unsigned int)f2bfbits(r1) << 16);
    *(unsigned int*)((unsigned short*)x2 + (size_t)n * 256 + c) = packed;
}

// ---------------- Layer 2 GEMM via MFMA: 32 nodes/block (R18-proven) ----------------
__global__ __launch_bounds__(256, 2)
void k_gemm2(const bf16* __restrict__ x2, const bf16* __restrict__ wt2,
             const float* __restrict__ aw_s, const float* __restrict__ aw_d,
             bf16* __restrict__ h2, float* __restrict__ as2,
             float* __restrict__ ad2) {
    int n0 = blockIdx.x * 32;
    int t = threadIdx.x;
    __shared__ bf16 xs[32 * 264];
    __shared__ float psPart[32][2];
    __shared__ float pdPart[32][2];
    for (int i = 0; i < 4; i++) {
        int idx = t + 256 * i;
        int r = idx >> 5, c8 = idx & 31;
        uint4 v;
        if (n0 + r < NN) v = *(const uint4*)(x2 + (size_t)(n0 + r) * 256 + c8 * 8);
        else             v = make_uint4(0, 0, 0, 0);
        *(uint4*)(&xs[r * 264 + c8 * 8]) = v;
    }
    __syncthreads();

    int wv = t >> 6, lane = t & 63;
    int q = lane >> 4, r16 = lane & 15;
    int rowBase = (wv & 1) * 16;
    int colBase = (wv >> 1) * 64;

    f32x4 acc[4];
#pragma unroll
    for (int ct = 0; ct < 4; ct++) acc[ct] = (f32x4){0.f, 0.f, 0.f, 0.f};

#pragma unroll
    for (int kt = 0; kt < 8; kt++) {
        v8bf va = *(const v8bf*)(&xs[(rowBase + r16) * 264 + kt * 32 + q * 8]);
#pragma unroll
        for (int ct = 0; ct < 4; ct++) {
            v8bf vb = *(const v8bf*)(wt2 + (size_t)(colBase + ct * 16 + r16) * 256 + kt * 32 + q * 8);
            acc[ct] = __builtin_amdgcn_mfma_f32_16x16x32_bf16(va, vb, acc[ct], 0, 0, 0);
        }
    }

    float wsv[4], wdv[4];
#pragma unroll
    for (int ct = 0; ct < 4; ct++) {
        int col = colBase + ct * 16 + r16;
        wsv[ct] = aw_s[col];
        wdv[ct] = aw_d[col];
    }

#pragma unroll
    for (int reg = 0; reg < 4; reg++) {
        int node = n0 + rowBase + q * 4 + reg;
        bool ok = node < NN;
        float ps = 0.f, pd = 0.f;
#pragma unroll
        for (int ct = 0; ct < 4; ct++) {
            float v = acc[ct][reg];
            if (ok) h2[(size_t)node * 128 + colBase + ct * 16 + r16] = __float2bfloat16(v);
            ps += v * wsv[ct];
            pd += v * wdv[ct];
        }
        for (int mask = 1; mask <= 8; mask <<= 1) {
            ps += __shfl_xor(ps, mask);
            pd += __shfl_xor(pd, mask);
        }
        if (r16 == 0) {
            int li = rowBase + q * 4 + reg;
            psPart[li][wv >> 1] = ps;
            pdPart[li][wv >> 1] = pd;
        }
    }
    __syncthreads();
    if (t < 32) {
        int node = n0 + t;
        if (node < NN) {
            as2[node] = psPart[t][0] + psPart[t][1];
            ad2[node] = pdPart[t][0] + pdPart[t][1];
        }
    }
}

// ---------------- FUSED Layer 2 gather + mean-pool accumulate.
// 8 waves/block = 8 consecutive nodes; wave computes its node's 128 outputs
// (R0-proven loop), stages fp32 results in LDS, then 128 threads do ONE global
// atomicAdd pass into gsum[graph][128] (batch sorted -> block usually 1 graph).
// Eliminates hf write (12.8MB) + k_pool read (12.8MB) + per-graph node loop.
__global__ __launch_bounds__(512, 2)
void k_gather2pool(const unsigned short* __restrict__ csrc, const int* __restrict__ deg,
                   const bf16* __restrict__ h2, const float* __restrict__ as2,
                   const float* __restrict__ ad2, const float* __restrict__ b2,
                   const int* __restrict__ batch, float* __restrict__ gsum) {
    int wv = threadIdx.x >> 6;          // 0..7
    int t = threadIdx.x & 63;           // lane
    int n = blockIdx.x * 8 + wv;        // NN % 8 == 0
    int cnt = min(deg[n], CAP);
    float adn = ad2[n];
    __shared__ unsigned int ls[8][CAP];
    __shared__ float la[8][CAP];
    __shared__ float acc[8][128];
    const char* h2c = (const char*)h2;
    unsigned int tconst = (unsigned int)t * 4;
    if (t < cnt) {
        int s = (int)csrc[n * CAP + t];
        ls[wv][t] = (unsigned int)s << 8;
        la[wv][t] = lrelu_exp(as2[s] + adn);
    }
    __syncthreads();
    const unsigned int* lsw = ls[wv];
    const float* law = la[wv];
    float a0 = 0.f, a1 = 0.f, ssum = 0.f;
    int j = 0;
    for (; j + 3 < cnt; j += 4) {
        unsigned int o0 = lsw[j] + tconst, o1 = lsw[j + 1] + tconst;
        unsigned int o2 = lsw[j + 2] + tconst, o3 = lsw[j + 3] + tconst;
        float A0 = law[j], A1 = law[j + 1], A2 = law[j + 2], A3 = law[j + 3];
        unsigned int u0 = *(const unsigned int*)(h2c + o0);
        unsigned int u1 = *(const unsigned int*)(h2c + o1);
        unsigned int u2 = *(const unsigned int*)(h2c + o2);
        unsigned int u3 = *(const unsigned int*)(h2c + o3);
        ssum += (A0 + A1) + (A2 + A3);
        a0 = fmaf(A0, lo2f(u0), a0); a0 = fmaf(A1, lo2f(u1), a0);
        a0 = fmaf(A2, lo2f(u2), a0); a0 = fmaf(A3, lo2f(u3), a0);
        a1 = fmaf(A0, hi2f(u0), a1); a1 = fmaf(A1, hi2f(u1), a1);
        a1 = fmaf(A2, hi2f(u2), a1); a1 = fmaf(A3, hi2f(u3), a1);
    }
    for (; j < cnt; j++) {
        unsigned int o0 = lsw[j] + tconst;
        float A0 = law[j];
        unsigned int u0 = *(const unsigned int*)(h2c + o0);
        ssum += A0;
        a0 = fmaf(A0, lo2f(u0), a0);
        a1 = fmaf(A0, hi2f(u0), a1);
    }
    float inv = 1.f / fmaxf(ssum, 1e-35f);
    int c = t * 2;
    float r0 = a0 * inv + b2[c + 0];
    float r1 = a1 * inv + b2[c + 1];
    r0 = r0 > 0.f ? r0 : (__expf(r0) - 1.f);
    r1 = r1 > 0.f ? r1 : (__expf(r1) - 1.f);
    acc[wv][c] = r0;
    acc[wv][c + 1] = r1;
    __syncthreads();
    int tt = threadIdx.x;
    if (tt < 128) {
        int n0 = blockIdx.x * 8;
        int b0 = batch[n0], b7 = batch[n0 + 7];
        if (b0 == b7) {
            float s = 0.f;
#pragma unroll
            for (int w = 0; w < 8; w++) s += acc[w][tt];
            atomicAdd(&gsum[b0 * 128 + tt], s);
        } else {
#pragma unroll
            for (int w = 0; w < 8; w++)
                atomicAdd(&gsum[batch[n0 + w] * 128 + tt], acc[w][tt]);
        }
    }
}

// ---------------- final: mean + linear + sigmoid from gsum (tiny) ----------------
__global__ void k_out(const float* __restrict__ gsum, const int* __restrict__ batch,
                      const float* __restrict__ Wl, const float* __restrict__ bl,
                      float* __restrict__ out) {
    int b = blockIdx.x;   // 0..511
    int t = threadIdx.x;  // 0..127
    int lo = 0, hi = NN;
    while (lo < hi) { int m = (lo + hi) >> 1; if (batch[m] < b) lo = m + 1; else hi = m; }
    int start = lo;
    int lo2 = start, hi2 = NN;
    while (lo2 < hi2) { int m = (lo2 + hi2) >> 1; if (batch[m] < b + 1) lo2 = m + 1; else hi2 = m; }
    int cnt = lo2 - start;
    float g = gsum[b * 128 + t] / (float)(cnt > 0 ? cnt : 1);
    float p = g * Wl[t];
    for (int o = 32; o > 0; o >>= 1) p += __shfl_down(p, o);
    __shared__ float red[2];
    if ((t & 63) == 0) red[t >> 6] = p;
    __syncthreads();
    if (t == 0) {
        float acc = red[0] + red[1] + bl[0];
        out[b] = 1.f / (1.f + __expf(-acc));
    }
}

extern "C" void kernel_launch(void* const* d_in, const int* in_sizes, int n_in,
                              void* d_out, int out_size, void* d_ws, size_t ws_size,
                              hipStream_t stream) {
    const float* x = (const float*)d_in[0];
    const int* ei = (const int*)d_in[1];
    const int* batch = (const int*)d_in[2];
    const float* W1 = (const float*)d_in[3];
    const float* aw_s1 = (const float*)d_in[4];
    const float* aw_d1 = (const float*)d_in[5];
    const float* b1 = (const float*)d_in[6];
    const float* W2 = (const float*)d_in[7];
    const float* aw_s2 = (const float*)d_in[8];
    const float* aw_d2 = (const float*)d_in[9];
    const float* b2 = (const float*)d_in[10];
    const float* Wl = (const float*)d_in[11];
    const float* bl = (const float*)d_in[12];
    const int* srcArr = ei;
    const int* dstArr = ei + EE;

    char* w = (char*)d_ws;
    size_t off = 0;
    auto alloc = [&](size_t bytes) -> void* {
        void* p = (void*)(w + off);
        off = (off + bytes + 255) & ~(size_t)255;
        return p;
    };
    bf16* bufA = (bf16*)alloc((size_t)NN * 256 * 2);   // h1; later h2
    bf16* bufB = (bf16*)alloc((size_t)NN * 256 * 2);   // x2
    unsigned short* csrc = (unsigned short*)alloc((size_t)NN * CAP * 2);  // 6.4 MB
    float* as1 = (float*)alloc((size_t)NN * 4 * 4);
    float* ad1 = (float*)alloc((size_t)NN * 4 * 4);
    float* as2 = (float*)alloc((size_t)NN * 4);
    float* ad2 = (float*)alloc((size_t)NN * 4);
    int* deg = (int*)alloc((size_t)NN * 4);
    float* gsum = (float*)alloc((size_t)BB * 128 * 4);   // 256 KB
    bf16* wt1 = (bf16*)alloc((size_t)256 * 128 * 2);
    bf16* wt2 = (bf16*)alloc((size_t)128 * 256 * 2);
    (void)ws_size;

    k_prep<<<256, 256, 0, stream>>>(W1, W2, wt1, wt2, deg, gsum);

    bf16* h1 = bufA;
    bf16* x2 = bufB;
    // fused: single-pass scatter (3321 blocks, 1 edge/thread) || gemm1 (1563 blocks)
    int gemmBlocks = (NN + 31) / 32;
    k_scatter_gemm1<<<SCAT_BLKS + gemmBlocks, 256, 0, stream>>>(
        srcArr, dstArr, deg, csrc, x, wt1, aw_s1, aw_d1, h1, as1, ad1);

    k_gather1<<<NN * 2, 64, 0, stream>>>(csrc, deg, h1, as1, ad1, b1, x2);

    bf16* h2 = bufA;  // h1 dead after gather1
    k_gemm2<<<gemmBlocks, 256, 0, stream>>>(x2, wt2, aw_s2, aw_d2, h2, as2, ad2);

    // fused gather2 + pool accumulate (8 nodes/block)
    k_gather2pool<<<NN / 8, 512, 0, stream>>>(csrc, deg, h2, as2, ad2, b2, batch, gsum);

    k_out<<<BB, 128, 0, stream>>>(gsum, batch, Wl, bl, (float*)d_out);
}